// Round 8
// baseline (2627.907 us; speedup 1.0000x reference)
//
#include <hip/hip_runtime.h>

#define N_NODES 50000
#define N_EDGES 800000
#define D 64
#define NUM_LAYERS 4
#define NUM_GRAPHS 128
#define N_ALL (2 * N_NODES)
#define E_ALL (2 * N_EDGES)
#define BSHIFT 9
#define NBUCK ((N_ALL + 511) / 512)     // 196 buckets of 512 dst ids
#define CHUNK 3072                      // edges per bin_scatter block (12/thread)
#define NCHUNK ((E_ALL + CHUNK - 1) / CHUNK)  // 521
#define CAP 12288                       // fixed slots per bucket (expected max ~8.6k)
#define NTILE (N_NODES / 16)            // 3125 node tiles of 16
#define GRID_MEGA 1536                  // 256 CU x 6 blocks/CU (launch_bounds-guaranteed)
#define BAR_GROUPS 8
#define BAR_QUOTA (GRID_MEGA / BAR_GROUPS)   // 192, exact

typedef __attribute__((ext_vector_type(8))) short bf16x8;   // 8 bf16 (4 VGPRs)
typedef __attribute__((ext_vector_type(4))) float f32x4;    // MFMA accumulator

// ---------- bf16 helpers (RNE pack, shift unpack) ----------
__device__ __forceinline__ unsigned f2bf(float f) {
    unsigned u = __float_as_uint(f);
    return (u + 0x7FFFu + ((u >> 16) & 1u)) >> 16;
}
__device__ __forceinline__ float bflo(unsigned p) { return __uint_as_float(p << 16); }
__device__ __forceinline__ float bfhi(unsigned p) { return __uint_as_float(p & 0xFFFF0000u); }
__device__ __forceinline__ void acc8(float* a, uint4 v) {
    a[0] += bflo(v.x); a[1] += bfhi(v.x);
    a[2] += bflo(v.y); a[3] += bfhi(v.y);
    a[4] += bflo(v.z); a[5] += bfhi(v.z);
    a[6] += bflo(v.w); a[7] += bfhi(v.w);
}

// ---------- pre-pass: x fp32 -> bf16; init cursors, pooled out, barrier state ----------
__global__ __launch_bounds__(256) void x_to_bf16(const float4* __restrict__ xf,
                                                 uint4* __restrict__ xb,
                                                 int* __restrict__ cursor,
                                                 float* __restrict__ out,
                                                 int* __restrict__ bar) {
    int t = threadIdx.x;
    if (blockIdx.x == 0 && t < NBUCK) cursor[t] = t * CAP;
    if (blockIdx.x == 1)
        for (int j = t; j < NUM_GRAPHS * D; j += 256) out[j] = 0.0f;
    if (blockIdx.x == 2 && t < 16) bar[t] = 0;   // cnt1[8], cnt2, gen
    int idx = blockIdx.x * 256 + t;          // one uint4 (8 bf16) per thread
    if (idx < N_NODES * D / 8) {
        float4 v0 = xf[(size_t)idx * 2];
        float4 v1 = xf[(size_t)idx * 2 + 1];
        uint4 o;
        o.x = f2bf(v0.x) | (f2bf(v0.y) << 16);
        o.y = f2bf(v0.z) | (f2bf(v0.w) << 16);
        o.z = f2bf(v1.x) | (f2bf(v1.y) << 16);
        o.w = f2bf(v1.z) | (f2bf(v1.w) << 16);
        xb[idx] = o;
    }
}

// ---------- pass 1: bin u32 pairs (d_low9<<16 | src16) into fixed-cap bucket regions ----------
__global__ __launch_bounds__(256) void bin_scatter(const int* __restrict__ sR,
                                                   const int* __restrict__ dR,
                                                   const int* __restrict__ sX,
                                                   const int* __restrict__ dX,
                                                   int* __restrict__ cursor,
                                                   unsigned* __restrict__ pairs) {
    __shared__ unsigned lpair[CHUNK];
    __shared__ unsigned char lbuck[CHUNK];
    __shared__ int lcnt[NBUCK];
    __shared__ int lbase[NBUCK];
    __shared__ int gbase[NBUCK];
    __shared__ int sc[256];
    __shared__ int tot;
    int t = threadIdx.x;
    for (int j = t; j < NBUCK; j += 256) lcnt[j] = 0;
    __syncthreads();

    int base = blockIdx.x * CHUNK;
    unsigned myp[12];
    int myr[12], myb[12];
#pragma unroll
    for (int i = 0; i < 12; ++i) {
        int e = base + i * 256 + t;
        if (e < E_ALL) {
            bool isR = (e < N_EDGES);
            int d = isR ? dR[e] : (N_NODES + dX[e - N_EDGES]);
            int s = isR ? sR[e] : sX[e - N_EDGES];
            myp[i] = ((unsigned)(d & 511) << 16) | (unsigned)s;
            myb[i] = d >> BSHIFT;
            myr[i] = atomicAdd(&lcnt[myb[i]], 1);
        }
    }
    __syncthreads();

    int v = (t < NBUCK) ? lcnt[t] : 0;
    sc[t] = v;
    __syncthreads();
    for (int off = 1; off < 256; off <<= 1) {
        int tv = (t >= off) ? sc[t - off] : 0;
        __syncthreads();
        sc[t] += tv;
        __syncthreads();
    }
    if (t < NBUCK) {
        lbase[t] = sc[t] - v;
        if (v > 0) gbase[t] = atomicAdd(&cursor[t], v);
    }
    if (t == NBUCK - 1) tot = sc[t];
    __syncthreads();

#pragma unroll
    for (int i = 0; i < 12; ++i) {
        int e = base + i * 256 + t;
        if (e < E_ALL) {
            int p = lbase[myb[i]] + myr[i];
            lpair[p] = myp[i];
            lbuck[p] = (unsigned char)myb[i];
        }
    }
    __syncthreads();

    int total = tot;
    for (int j = t; j < total; j += 256) {
        int b = lbuck[j];
        pairs[(size_t)gbase[b] + (j - lbase[b])] = lpair[j];
    }
}

// ---------- pass 2: per bucket -- degrees in LDS, beg/end arrays, place col ----------
__global__ __launch_bounds__(256) void bucket_place(const unsigned* __restrict__ pairs,
                                                    const int* __restrict__ cursor,
                                                    int* __restrict__ begA,
                                                    int* __restrict__ endA,
                                                    unsigned short* __restrict__ col) {
    __shared__ unsigned short scol[CAP];
    __shared__ int ldeg[512];
    __shared__ int lcur[512];
    __shared__ int s1[256];
    int b = blockIdx.x;
    int d0 = b << BSHIFT;
    int nd = min(512, N_ALL - d0);
    int t = threadIdx.x;
    int base = b * CAP;
    int cnt = cursor[b] - base;
    ldeg[t] = 0; ldeg[t + 256] = 0;
    __syncthreads();
    for (int i = t; i < cnt; i += 256) {
        int dl = pairs[(size_t)base + i] >> 16;
        atomicAdd(&ldeg[dl], 1);
    }
    __syncthreads();
    int v0 = ldeg[2 * t], v1 = ldeg[2 * t + 1];
    int pv = v0 + v1;
    s1[t] = pv;
    __syncthreads();
    for (int off = 1; off < 256; off <<= 1) {
        int tv = (t >= off) ? s1[t - off] : 0;
        __syncthreads();
        s1[t] += tv;
        __syncthreads();
    }
    int before = s1[t] - pv;
    lcur[2 * t] = before;
    lcur[2 * t + 1] = before + v0;
    if (2 * t < nd) {
        begA[d0 + 2 * t] = base + before;
        endA[d0 + 2 * t] = base + before + v0;
    }
    if (2 * t + 1 < nd) {
        begA[d0 + 2 * t + 1] = base + before + v0;
        endA[d0 + 2 * t + 1] = base + before + v0 + v1;
    }
    __syncthreads();
    for (int i = t; i < cnt; i += 256) {
        unsigned pr = pairs[(size_t)base + i];
        int dl = pr >> 16;
        int p = atomicAdd(&lcur[dl], 1);
        scol[p] = (unsigned short)(pr & 0xFFFFu);
    }
    __syncthreads();
    for (int i = t; i < cnt; i += 256) col[base + i] = scol[i];
}

// ---------- shared gather helper: a[8] += sum of neighbor rows (split-edge, unroll 8) ----------
__device__ __forceinline__ void gather_rows(const uint4* __restrict__ xb,
                                            const unsigned short* __restrict__ cp,
                                            int ch, int ln8, float* a) {
    int i = 0;
    for (; i + 8 <= ch; i += 8) {
        int s0 = cp[2 * i],      s1 = cp[2 * i + 2],  s2 = cp[2 * i + 4],  s3 = cp[2 * i + 6];
        int s4 = cp[2 * i + 8],  s5 = cp[2 * i + 10], s6 = cp[2 * i + 12], s7 = cp[2 * i + 14];
        uint4 v0 = xb[(size_t)s0 * 8 + ln8];
        uint4 v1 = xb[(size_t)s1 * 8 + ln8];
        uint4 v2 = xb[(size_t)s2 * 8 + ln8];
        uint4 v3 = xb[(size_t)s3 * 8 + ln8];
        uint4 v4 = xb[(size_t)s4 * 8 + ln8];
        uint4 v5 = xb[(size_t)s5 * 8 + ln8];
        uint4 v6 = xb[(size_t)s6 * 8 + ln8];
        uint4 v7 = xb[(size_t)s7 * 8 + ln8];
        acc8(a, v0); acc8(a, v1); acc8(a, v2); acc8(a, v3);
        acc8(a, v4); acc8(a, v5); acc8(a, v6); acc8(a, v7);
    }
    for (; i + 4 <= ch; i += 4) {
        int s0 = cp[2 * i], s1 = cp[2 * i + 2], s2 = cp[2 * i + 4], s3 = cp[2 * i + 6];
        uint4 v0 = xb[(size_t)s0 * 8 + ln8];
        uint4 v1 = xb[(size_t)s1 * 8 + ln8];
        uint4 v2 = xb[(size_t)s2 * 8 + ln8];
        uint4 v3 = xb[(size_t)s3 * 8 + ln8];
        acc8(a, v0); acc8(a, v1); acc8(a, v2); acc8(a, v3);
    }
    for (; i < ch; ++i) acc8(a, xb[(size_t)cp[2 * i] * 8 + ln8]);
}

// ---------- grid barrier: two-level (8x192), sense-reversing, agent-scope ----------
// bar[0..7]=cnt1, bar[8]=cnt2, bar[9]=gen. Bounded spin: capacity failure -> wrong
// answer (passed:false), never a hang.
__device__ __forceinline__ void grid_barrier(int* bar, int bgrp) {
    __syncthreads();                      // drain this block's stores (waitcnt before barrier)
    if (threadIdx.x == 0) {
        __threadfence();                  // release: write back this XCD's L2
        int g0 = __hip_atomic_load(&bar[9], __ATOMIC_RELAXED, __HIP_MEMORY_SCOPE_AGENT);
        int a = __hip_atomic_fetch_add(&bar[bgrp], 1, __ATOMIC_ACQ_REL, __HIP_MEMORY_SCOPE_AGENT);
        bool release = false;
        if (a == BAR_QUOTA - 1) {
            __hip_atomic_store(&bar[bgrp], 0, __ATOMIC_RELAXED, __HIP_MEMORY_SCOPE_AGENT);
            int b = __hip_atomic_fetch_add(&bar[8], 1, __ATOMIC_ACQ_REL, __HIP_MEMORY_SCOPE_AGENT);
            if (b == BAR_GROUPS - 1) {
                __hip_atomic_store(&bar[8], 0, __ATOMIC_RELAXED, __HIP_MEMORY_SCOPE_AGENT);
                __hip_atomic_fetch_add(&bar[9], 1, __ATOMIC_ACQ_REL, __HIP_MEMORY_SCOPE_AGENT);
                release = true;
            }
        }
        if (!release) {
            int spins = 0;
            while (__hip_atomic_load(&bar[9], __ATOMIC_ACQUIRE, __HIP_MEMORY_SCOPE_AGENT) == g0) {
                __builtin_amdgcn_s_sleep(8);
                if (++spins > 1000000) break;   // ~0.2s escape hatch
            }
        }
        __threadfence();                  // acquire: invalidate stale L1/L2
    }
    __syncthreads();
}

// ---------- mega kernel: 4 x (gather+MFMA-linear+relu ; expander gather) + fused pool ----------
__global__ __launch_bounds__(256, 6) void gin_mega(unsigned short* __restrict__ A_,
                                                   unsigned short* __restrict__ B_,
                                                   const int* __restrict__ begA,
                                                   const int* __restrict__ endA,
                                                   const unsigned short* __restrict__ col,
                                                   const float* __restrict__ Ws,
                                                   const float* __restrict__ bs,
                                                   const int* __restrict__ batch,
                                                   float* __restrict__ out,
                                                   int* __restrict__ bar) {
    __shared__ __align__(16) unsigned short hlb[16 * 72];       // h bf16, stride 72
    __shared__ __align__(16) unsigned short Wb[4 * 2 * 64 * 8]; // B-frags [wave][kk][lane][8]
    __shared__ float sacc[16 * 64];                             // pool staging
    int t = threadIdx.x;
    int bgrp = blockIdx.x & (BAR_GROUPS - 1);
    int wv = t >> 6, lane = t & 63;
    int lo16 = lane & 15, hi4 = lane >> 4;
    int g16 = t >> 4;               // node group within tile
    int half = (t >> 3) & 1;
    int ln8 = t & 7;
    const int* begX = begA + N_NODES;
    const int* endX = endA + N_NODES;

    for (int l = 0; l < NUM_LAYERS; ++l) {
        // ---- Wb precompute for layer l: Wb[wv][kk][lane][j] = W[wv*16+lo16][kk*32+hi4*8+j]
        {
            const float* wp = Ws + (size_t)l * D * D + (wv * 16 + lo16) * 64 + hi4 * 8;
#pragma unroll
            for (int kk = 0; kk < 2; ++kk) {
                float4 w0 = *(const float4*)(wp + kk * 32);
                float4 w1 = *(const float4*)(wp + kk * 32 + 4);
                uint4 pk;
                pk.x = f2bf(w0.x) | (f2bf(w0.y) << 16);
                pk.y = f2bf(w0.z) | (f2bf(w0.w) << 16);
                pk.z = f2bf(w1.x) | (f2bf(w1.y) << 16);
                pk.w = f2bf(w1.z) | (f2bf(w1.w) << 16);
                *(uint4*)&Wb[((wv * 2 + kk) * 64 + lane) * 8] = pk;
            }
        }
        float bo = bs[(size_t)l * D + lane];
        __syncthreads();

        // ---- phase GL: A_ = relu((B_ + gather_real(B_)) @ W^T + b) ----
        const uint4* xb = (const uint4*)B_;
        for (int tile = blockIdx.x; tile < NTILE; tile += GRID_MEGA) {
            int node = tile * 16 + g16;
            int beg = begA[node], end = endA[node];
            int cnt = end - beg;
            int ch = (cnt - half + 1) >> 1;
            const unsigned short* cp = col + beg + half;
            float a[8];
            if (half == 0) {
                uint4 v = xb[(size_t)node * 8 + ln8];
                a[0] = bflo(v.x); a[1] = bfhi(v.x); a[2] = bflo(v.y); a[3] = bfhi(v.y);
                a[4] = bflo(v.z); a[5] = bfhi(v.z); a[6] = bflo(v.w); a[7] = bfhi(v.w);
            } else {
#pragma unroll
                for (int i = 0; i < 8; ++i) a[i] = 0.0f;
            }
            gather_rows(xb, cp, ch, ln8, a);
#pragma unroll
            for (int j = 0; j < 8; ++j) a[j] += __shfl_xor(a[j], 8);
            if (half == 0) {
                uint4 o4;
                o4.x = f2bf(a[0]) | (f2bf(a[1]) << 16);
                o4.y = f2bf(a[2]) | (f2bf(a[3]) << 16);
                o4.z = f2bf(a[4]) | (f2bf(a[5]) << 16);
                o4.w = f2bf(a[6]) | (f2bf(a[7]) << 16);
                *(uint4*)&hlb[g16 * 72 + ln8 * 8] = o4;
            }
            __syncthreads();

            f32x4 acc = {0.0f, 0.0f, 0.0f, 0.0f};
            bf16x8 a0 = *(const bf16x8*)&hlb[lo16 * 72 + hi4 * 8];
            bf16x8 a1 = *(const bf16x8*)&hlb[lo16 * 72 + 32 + hi4 * 8];
            bf16x8 b0 = *(const bf16x8*)&Wb[((wv * 2 + 0) * 64 + lane) * 8];
            bf16x8 b1 = *(const bf16x8*)&Wb[((wv * 2 + 1) * 64 + lane) * 8];
            acc = __builtin_amdgcn_mfma_f32_16x16x32_bf16(a0, b0, acc, 0, 0, 0);
            acc = __builtin_amdgcn_mfma_f32_16x16x32_bf16(a1, b1, acc, 0, 0, 0);

            int o = wv * 16 + lo16;
            size_t nbase = (size_t)tile * 16;
#pragma unroll
            for (int r = 0; r < 4; ++r) {
                int nr = hi4 * 4 + r;
                A_[(nbase + nr) * 64 + o] = (unsigned short)f2bf(fmaxf(acc[r] + bo, 0.0f));
            }
            __syncthreads();   // hlb reused next tile
        }
        grid_barrier(bar, bgrp);

        // ---- phase GX: B_ = A_ + gather_expander(A_)  (last layer: fused pool) ----
        const uint4* yb = (const uint4*)A_;
        for (int tile = blockIdx.x; tile < NTILE; tile += GRID_MEGA) {
            int nbase = tile * 16;
            int node = nbase + g16;
            int beg = begX[node], end = endX[node];
            int cnt = end - beg;
            int ch = (cnt - half + 1) >> 1;
            const unsigned short* cp = col + beg + half;
            float a[8];
            if (half == 0) {
                uint4 v = yb[(size_t)node * 8 + ln8];
                a[0] = bflo(v.x); a[1] = bfhi(v.x); a[2] = bflo(v.y); a[3] = bfhi(v.y);
                a[4] = bflo(v.z); a[5] = bfhi(v.z); a[6] = bflo(v.w); a[7] = bfhi(v.w);
            } else {
#pragma unroll
                for (int i = 0; i < 8; ++i) a[i] = 0.0f;
            }
            gather_rows(yb, cp, ch, ln8, a);
#pragma unroll
            for (int j = 0; j < 8; ++j) a[j] += __shfl_xor(a[j], 8);
            if (l < NUM_LAYERS - 1) {
                if (half == 0) {
                    uint4 o;
                    o.x = f2bf(a[0]) | (f2bf(a[1]) << 16);
                    o.y = f2bf(a[2]) | (f2bf(a[3]) << 16);
                    o.z = f2bf(a[4]) | (f2bf(a[5]) << 16);
                    o.w = f2bf(a[6]) | (f2bf(a[7]) << 16);
                    ((uint4*)B_)[(size_t)node * 8 + ln8] = o;
                }
            } else {
                if (half == 0) {
                    float4* sp = (float4*)(sacc + g16 * 64 + ln8 * 8);
                    sp[0] = make_float4(a[0], a[1], a[2], a[3]);
                    sp[1] = make_float4(a[4], a[5], a[6], a[7]);
                }
                __syncthreads();
                if (t < 64) {   // per-graph run-length reduce, <=2-3 atomics per col
                    int gprev = batch[nbase];
                    float pacc = 0.0f;
                    for (int r = 0; r < 16; ++r) {
                        int g = batch[nbase + r];
                        float v = sacc[r * 64 + t];
                        if (g != gprev) {
                            atomicAdd(&out[(size_t)gprev * D + t], pacc);
                            pacc = 0.0f;
                            gprev = g;
                        }
                        pacc += v;
                    }
                    atomicAdd(&out[(size_t)gprev * D + t], pacc);
                }
                __syncthreads();   // sacc reused next tile
            }
        }
        if (l < NUM_LAYERS - 1) grid_barrier(bar, bgrp);
    }
}

// ---------- host ----------
extern "C" void kernel_launch(void* const* d_in, const int* in_sizes, int n_in,
                              void* d_out, int out_size, void* d_ws, size_t ws_size,
                              hipStream_t stream) {
    const float* x_in  = (const float*)d_in[0];
    const int*   ei    = (const int*)d_in[1];
    const int*   eei   = (const int*)d_in[2];
    const int*   batch = (const int*)d_in[3];
    const float* Ws    = (const float*)d_in[4];
    const float* bs    = (const float*)d_in[5];
    float* out = (float*)d_out;

    unsigned short* A = (unsigned short*)d_ws;          // y (bf16) [N*D]
    unsigned short* B = A + (size_t)N_NODES * D;        // x / x' (bf16)
    unsigned short* colAll = B + (size_t)N_NODES * D;   // u16 col [NBUCK*CAP] (holed CSR)
    unsigned* pairs = (unsigned*)(colAll + (size_t)NBUCK * CAP);  // u32 [NBUCK*CAP]
    int* p = (int*)(pairs + (size_t)NBUCK * CAP);
    int* begA = p;          p += N_ALL;
    int* endA = p;          p += N_ALL;
    int* cursor = p;        p += NBUCK;
    int* bar = p;           p += 16;

    const int* e_src = ei;
    const int* e_dst = ei + N_EDGES;
    const int* x_src = eei;
    const int* x_dst = eei + N_EDGES;

    dim3 blk(256);

    // input fp32 -> bf16 (into B); init cursors, pooled out, barrier state
    const int cgrid = (N_NODES * D / 8 + 255) / 256;   // 1563
    x_to_bf16<<<cgrid, blk, 0, stream>>>((const float4*)x_in, (uint4*)B, cursor, out, bar);

    // CSR build: 2 kernels (fixed-cap buckets)
    bin_scatter<<<NCHUNK, blk, 0, stream>>>(e_src, e_dst, x_src, x_dst, cursor, pairs);
    bucket_place<<<NBUCK, blk, 0, stream>>>(pairs, cursor, begA, endA, colAll);

    // all 4 layers + pool: ONE persistent kernel with software grid barriers
    gin_mega<<<dim3(GRID_MEGA), blk, 0, stream>>>(A, B, begA, endA, colAll,
                                                  Ws, bs, batch, out, bar);
}

// Round 9
// 1845.556 us; speedup vs baseline: 1.4239x; 1.4239x over previous
//
#include <hip/hip_runtime.h>

#define N_NODES 50000
#define N_EDGES 800000
#define D 64
#define NUM_LAYERS 4
#define NUM_GRAPHS 128
#define N_ALL (2 * N_NODES)
#define E_ALL (2 * N_EDGES)
#define BSHIFT 9
#define NBUCK ((N_ALL + 511) / 512)     // 196 buckets of 512 dst ids
#define CHUNK 3072                      // edges per bin_scatter block (12/thread)
#define NCHUNK ((E_ALL + CHUNK - 1) / CHUNK)  // 521
#define CAP 12288                       // fixed slots per bucket (expected max ~8.6k)
#define NTILE (N_NODES / 16)            // 3125 node tiles of 16
#define GRID_MEGA 2048                  // 256 CU x 8 blocks/CU (launch_bounds-guaranteed)
#define BAR_GROUPS 8
#define BAR_QUOTA (GRID_MEGA / BAR_GROUPS)   // 256, exact
#define ESCAPE 500000                   // bounded spin: fail slow, never hang

typedef __attribute__((ext_vector_type(8))) short bf16x8;   // 8 bf16 (4 VGPRs)
typedef __attribute__((ext_vector_type(4))) float f32x4;    // MFMA accumulator

// ---------- bf16 helpers (RNE pack, shift unpack) ----------
__device__ __forceinline__ unsigned f2bf(float f) {
    unsigned u = __float_as_uint(f);
    return (u + 0x7FFFu + ((u >> 16) & 1u)) >> 16;
}
__device__ __forceinline__ float bflo(unsigned p) { return __uint_as_float(p << 16); }
__device__ __forceinline__ float bfhi(unsigned p) { return __uint_as_float(p & 0xFFFF0000u); }
__device__ __forceinline__ void acc8(float* a, uint4 v) {
    a[0] += bflo(v.x); a[1] += bfhi(v.x);
    a[2] += bflo(v.y); a[3] += bfhi(v.y);
    a[4] += bflo(v.z); a[5] += bfhi(v.z);
    a[6] += bflo(v.w); a[7] += bfhi(v.w);
}

// ---------- pre-pass: x fp32 -> bf16; init cursors, pooled out, barrier state ----------
__global__ __launch_bounds__(256) void x_to_bf16(const float4* __restrict__ xf,
                                                 uint4* __restrict__ xb,
                                                 int* __restrict__ cursor,
                                                 float* __restrict__ out,
                                                 int* __restrict__ bar) {
    int t = threadIdx.x;
    if (blockIdx.x == 0 && t < NBUCK) cursor[t] = t * CAP;
    if (blockIdx.x == 1)
        for (int j = t; j < NUM_GRAPHS * D; j += 256) out[j] = 0.0f;
    if (blockIdx.x == 2 && t < 32) bar[t] = 0;   // grp[8], lvl2, gen, flushDone, arrivedGen, xcdClaim[8]
    int idx = blockIdx.x * 256 + t;          // one uint4 (8 bf16) per thread
    if (idx < N_NODES * D / 8) {
        float4 v0 = xf[(size_t)idx * 2];
        float4 v1 = xf[(size_t)idx * 2 + 1];
        uint4 o;
        o.x = f2bf(v0.x) | (f2bf(v0.y) << 16);
        o.y = f2bf(v0.z) | (f2bf(v0.w) << 16);
        o.z = f2bf(v1.x) | (f2bf(v1.y) << 16);
        o.w = f2bf(v1.z) | (f2bf(v1.w) << 16);
        xb[idx] = o;
    }
}

// ---------- pass 1: bin u32 pairs (d_low9<<16 | src16) into fixed-cap bucket regions ----------
__global__ __launch_bounds__(256) void bin_scatter(const int* __restrict__ sR,
                                                   const int* __restrict__ dR,
                                                   const int* __restrict__ sX,
                                                   const int* __restrict__ dX,
                                                   int* __restrict__ cursor,
                                                   unsigned* __restrict__ pairs) {
    __shared__ unsigned lpair[CHUNK];
    __shared__ unsigned char lbuck[CHUNK];
    __shared__ int lcnt[NBUCK];
    __shared__ int lbase[NBUCK];
    __shared__ int gbase[NBUCK];
    __shared__ int sc[256];
    __shared__ int tot;
    int t = threadIdx.x;
    for (int j = t; j < NBUCK; j += 256) lcnt[j] = 0;
    __syncthreads();

    int base = blockIdx.x * CHUNK;
    unsigned myp[12];
    int myr[12], myb[12];
#pragma unroll
    for (int i = 0; i < 12; ++i) {
        int e = base + i * 256 + t;
        if (e < E_ALL) {
            bool isR = (e < N_EDGES);
            int d = isR ? dR[e] : (N_NODES + dX[e - N_EDGES]);
            int s = isR ? sR[e] : sX[e - N_EDGES];
            myp[i] = ((unsigned)(d & 511) << 16) | (unsigned)s;
            myb[i] = d >> BSHIFT;
            myr[i] = atomicAdd(&lcnt[myb[i]], 1);
        }
    }
    __syncthreads();

    int v = (t < NBUCK) ? lcnt[t] : 0;
    sc[t] = v;
    __syncthreads();
    for (int off = 1; off < 256; off <<= 1) {
        int tv = (t >= off) ? sc[t - off] : 0;
        __syncthreads();
        sc[t] += tv;
        __syncthreads();
    }
    if (t < NBUCK) {
        lbase[t] = sc[t] - v;
        if (v > 0) gbase[t] = atomicAdd(&cursor[t], v);
    }
    if (t == NBUCK - 1) tot = sc[t];
    __syncthreads();

#pragma unroll
    for (int i = 0; i < 12; ++i) {
        int e = base + i * 256 + t;
        if (e < E_ALL) {
            int p = lbase[myb[i]] + myr[i];
            lpair[p] = myp[i];
            lbuck[p] = (unsigned char)myb[i];
        }
    }
    __syncthreads();

    int total = tot;
    for (int j = t; j < total; j += 256) {
        int b = lbuck[j];
        pairs[(size_t)gbase[b] + (j - lbase[b])] = lpair[j];
    }
}

// ---------- pass 2: per bucket -- degrees in LDS, beg/end arrays, place col ----------
__global__ __launch_bounds__(256) void bucket_place(const unsigned* __restrict__ pairs,
                                                    const int* __restrict__ cursor,
                                                    int* __restrict__ begA,
                                                    int* __restrict__ endA,
                                                    unsigned short* __restrict__ col) {
    __shared__ unsigned short scol[CAP];
    __shared__ int ldeg[512];
    __shared__ int lcur[512];
    __shared__ int s1[256];
    int b = blockIdx.x;
    int d0 = b << BSHIFT;
    int nd = min(512, N_ALL - d0);
    int t = threadIdx.x;
    int base = b * CAP;
    int cnt = cursor[b] - base;
    ldeg[t] = 0; ldeg[t + 256] = 0;
    __syncthreads();
    for (int i = t; i < cnt; i += 256) {
        int dl = pairs[(size_t)base + i] >> 16;
        atomicAdd(&ldeg[dl], 1);
    }
    __syncthreads();
    int v0 = ldeg[2 * t], v1 = ldeg[2 * t + 1];
    int pv = v0 + v1;
    s1[t] = pv;
    __syncthreads();
    for (int off = 1; off < 256; off <<= 1) {
        int tv = (t >= off) ? s1[t - off] : 0;
        __syncthreads();
        s1[t] += tv;
        __syncthreads();
    }
    int before = s1[t] - pv;
    lcur[2 * t] = before;
    lcur[2 * t + 1] = before + v0;
    if (2 * t < nd) {
        begA[d0 + 2 * t] = base + before;
        endA[d0 + 2 * t] = base + before + v0;
    }
    if (2 * t + 1 < nd) {
        begA[d0 + 2 * t + 1] = base + before + v0;
        endA[d0 + 2 * t + 1] = base + before + v0 + v1;
    }
    __syncthreads();
    for (int i = t; i < cnt; i += 256) {
        unsigned pr = pairs[(size_t)base + i];
        int dl = pr >> 16;
        int p = atomicAdd(&lcur[dl], 1);
        scol[p] = (unsigned short)(pr & 0xFFFFu);
    }
    __syncthreads();
    for (int i = t; i < cnt; i += 256) col[base + i] = scol[i];
}

// ---------- shared gather helper: a[8] += sum of neighbor rows (split-edge, unroll 8) ----------
__device__ __forceinline__ void gather_rows(const uint4* __restrict__ xb,
                                            const unsigned short* __restrict__ cp,
                                            int ch, int ln8, float* a) {
    int i = 0;
    for (; i + 8 <= ch; i += 8) {
        int s0 = cp[2 * i],      s1 = cp[2 * i + 2],  s2 = cp[2 * i + 4],  s3 = cp[2 * i + 6];
        int s4 = cp[2 * i + 8],  s5 = cp[2 * i + 10], s6 = cp[2 * i + 12], s7 = cp[2 * i + 14];
        uint4 v0 = xb[(size_t)s0 * 8 + ln8];
        uint4 v1 = xb[(size_t)s1 * 8 + ln8];
        uint4 v2 = xb[(size_t)s2 * 8 + ln8];
        uint4 v3 = xb[(size_t)s3 * 8 + ln8];
        uint4 v4 = xb[(size_t)s4 * 8 + ln8];
        uint4 v5 = xb[(size_t)s5 * 8 + ln8];
        uint4 v6 = xb[(size_t)s6 * 8 + ln8];
        uint4 v7 = xb[(size_t)s7 * 8 + ln8];
        acc8(a, v0); acc8(a, v1); acc8(a, v2); acc8(a, v3);
        acc8(a, v4); acc8(a, v5); acc8(a, v6); acc8(a, v7);
    }
    for (; i + 4 <= ch; i += 4) {
        int s0 = cp[2 * i], s1 = cp[2 * i + 2], s2 = cp[2 * i + 4], s3 = cp[2 * i + 6];
        uint4 v0 = xb[(size_t)s0 * 8 + ln8];
        uint4 v1 = xb[(size_t)s1 * 8 + ln8];
        uint4 v2 = xb[(size_t)s2 * 8 + ln8];
        uint4 v3 = xb[(size_t)s3 * 8 + ln8];
        acc8(a, v0); acc8(a, v1); acc8(a, v2); acc8(a, v3);
    }
    for (; i < ch; ++i) acc8(a, xb[(size_t)cp[2 * i] * 8 + ln8]);
}

// ---------- grid barrier v2: relaxed counters + per-XCD leader flush ----------
// bar: [0..7] group arrival, [8] lvl2, [9] gen (release), [10] flushDone,
//      [12] allArrived gen, [16..23] per-XCD leader claim (gen-tagged).
// All atomics RELAXED (no implicit per-block L2 flush). Only the 8 XCD leaders run
// __threadfence() (compiler-emitted wbl2+inv for their XCD). Every block does a
// CU-scope buffer_inv (L1 only, cheap) after release. Bounded spins: capacity or
// XCC_ID failure -> slow wrong answer (passed:false), never a hang.
__device__ __forceinline__ void grid_barrier(int* bar, int bgrp, int xcd) {
    __syncthreads();   // compiler drains each wave's vmcnt before s_barrier -> stores in L2
    if (threadIdx.x == 0) {
        asm volatile("s_waitcnt vmcnt(0) lgkmcnt(0)" ::: "memory");
        int g0 = __hip_atomic_load(&bar[9], __ATOMIC_RELAXED, __HIP_MEMORY_SCOPE_AGENT);
        // arrival, two-level
        if (__hip_atomic_fetch_add(&bar[bgrp], 1, __ATOMIC_RELAXED, __HIP_MEMORY_SCOPE_AGENT)
            == BAR_QUOTA - 1) {
            __hip_atomic_store(&bar[bgrp], 0, __ATOMIC_RELAXED, __HIP_MEMORY_SCOPE_AGENT);
            if (__hip_atomic_fetch_add(&bar[8], 1, __ATOMIC_RELAXED, __HIP_MEMORY_SCOPE_AGENT)
                == BAR_GROUPS - 1) {
                __hip_atomic_store(&bar[8], 0, __ATOMIC_RELAXED, __HIP_MEMORY_SCOPE_AGENT);
                __hip_atomic_fetch_add(&bar[12], 1, __ATOMIC_RELAXED, __HIP_MEMORY_SCOPE_AGENT);
            }
        }
        // per-XCD leader election for this generation
        int expected = g0;
        bool leader = __hip_atomic_compare_exchange_strong(
            &bar[16 + xcd], &expected, g0 + 1,
            __ATOMIC_RELAXED, __ATOMIC_RELAXED, __HIP_MEMORY_SCOPE_AGENT);
        if (leader) {
            int spins = 0;
            while (__hip_atomic_load(&bar[12], __ATOMIC_RELAXED, __HIP_MEMORY_SCOPE_AGENT) == g0) {
                __builtin_amdgcn_s_sleep(2);
                if (++spins > ESCAPE) break;
            }
            __threadfence();   // agent fence: wbl2 + inv for THIS XCD's L2 (compiler-emitted)
            if (__hip_atomic_fetch_add(&bar[10], 1, __ATOMIC_RELAXED, __HIP_MEMORY_SCOPE_AGENT)
                == BAR_GROUPS - 1) {
                __hip_atomic_store(&bar[10], 0, __ATOMIC_RELAXED, __HIP_MEMORY_SCOPE_AGENT);
                __hip_atomic_fetch_add(&bar[9], 1, __ATOMIC_RELAXED, __HIP_MEMORY_SCOPE_AGENT);
            }
        }
        int spins = 0;
        while (__hip_atomic_load(&bar[9], __ATOMIC_RELAXED, __HIP_MEMORY_SCOPE_AGENT) == g0) {
            __builtin_amdgcn_s_sleep(8);
            if (++spins > ESCAPE) break;
        }
        asm volatile("buffer_inv" ::: "memory");   // CU scope: invalidate this CU's L1
    }
    __syncthreads();
}

// ---------- mega kernel: 4 x (gather+MFMA-linear+relu ; expander gather) + fused pool ----------
__global__ __launch_bounds__(256, 8) void gin_mega(unsigned short* __restrict__ A_,
                                                   unsigned short* __restrict__ B_,
                                                   const int* __restrict__ begA,
                                                   const int* __restrict__ endA,
                                                   const unsigned short* __restrict__ col,
                                                   const float* __restrict__ Ws,
                                                   const float* __restrict__ bs,
                                                   const int* __restrict__ batch,
                                                   float* __restrict__ out,
                                                   int* __restrict__ bar) {
    __shared__ __align__(16) unsigned short hlb[16 * 72];       // h bf16, stride 72
    __shared__ __align__(16) unsigned short Wb[4 * 2 * 64 * 8]; // B-frags [wave][kk][lane][8]
    __shared__ float sacc[16 * 64];                             // pool staging
    int t = threadIdx.x;
    int bgrp = blockIdx.x & (BAR_GROUPS - 1);
    int xcd = 0;
    asm("s_getreg_b32 %0, hwreg(HW_REG_XCC_ID)" : "=s"(xcd));
    xcd &= 7;
    int wv = t >> 6, lane = t & 63;
    int lo16 = lane & 15, hi4 = lane >> 4;
    int g16 = t >> 4;               // node group within tile
    int half = (t >> 3) & 1;
    int ln8 = t & 7;
    const int* begX = begA + N_NODES;
    const int* endX = endA + N_NODES;

    for (int l = 0; l < NUM_LAYERS; ++l) {
        // ---- Wb precompute for layer l ----
        {
            const float* wp = Ws + (size_t)l * D * D + (wv * 16 + lo16) * 64 + hi4 * 8;
#pragma unroll
            for (int kk = 0; kk < 2; ++kk) {
                float4 w0 = *(const float4*)(wp + kk * 32);
                float4 w1 = *(const float4*)(wp + kk * 32 + 4);
                uint4 pk;
                pk.x = f2bf(w0.x) | (f2bf(w0.y) << 16);
                pk.y = f2bf(w0.z) | (f2bf(w0.w) << 16);
                pk.z = f2bf(w1.x) | (f2bf(w1.y) << 16);
                pk.w = f2bf(w1.z) | (f2bf(w1.w) << 16);
                *(uint4*)&Wb[((wv * 2 + kk) * 64 + lane) * 8] = pk;
            }
        }
        float bo = bs[(size_t)l * D + lane];
        __syncthreads();

        // ---- phase GL: A_ = relu((B_ + gather_real(B_)) @ W^T + b) ----
        const uint4* xb = (const uint4*)B_;
        for (int tile = blockIdx.x; tile < NTILE; tile += GRID_MEGA) {
            int node = tile * 16 + g16;
            int beg = begA[node], end = endA[node];
            int cnt = end - beg;
            int ch = (cnt - half + 1) >> 1;
            const unsigned short* cp = col + beg + half;
            float a[8];
            if (half == 0) {
                uint4 v = xb[(size_t)node * 8 + ln8];
                a[0] = bflo(v.x); a[1] = bfhi(v.x); a[2] = bflo(v.y); a[3] = bfhi(v.y);
                a[4] = bflo(v.z); a[5] = bfhi(v.z); a[6] = bflo(v.w); a[7] = bfhi(v.w);
            } else {
#pragma unroll
                for (int i = 0; i < 8; ++i) a[i] = 0.0f;
            }
            gather_rows(xb, cp, ch, ln8, a);
#pragma unroll
            for (int j = 0; j < 8; ++j) a[j] += __shfl_xor(a[j], 8);
            if (half == 0) {
                uint4 o4;
                o4.x = f2bf(a[0]) | (f2bf(a[1]) << 16);
                o4.y = f2bf(a[2]) | (f2bf(a[3]) << 16);
                o4.z = f2bf(a[4]) | (f2bf(a[5]) << 16);
                o4.w = f2bf(a[6]) | (f2bf(a[7]) << 16);
                *(uint4*)&hlb[g16 * 72 + ln8 * 8] = o4;
            }
            __syncthreads();

            f32x4 acc = {0.0f, 0.0f, 0.0f, 0.0f};
            bf16x8 a0 = *(const bf16x8*)&hlb[lo16 * 72 + hi4 * 8];
            bf16x8 a1 = *(const bf16x8*)&hlb[lo16 * 72 + 32 + hi4 * 8];
            bf16x8 b0 = *(const bf16x8*)&Wb[((wv * 2 + 0) * 64 + lane) * 8];
            bf16x8 b1 = *(const bf16x8*)&Wb[((wv * 2 + 1) * 64 + lane) * 8];
            acc = __builtin_amdgcn_mfma_f32_16x16x32_bf16(a0, b0, acc, 0, 0, 0);
            acc = __builtin_amdgcn_mfma_f32_16x16x32_bf16(a1, b1, acc, 0, 0, 0);

            int o = wv * 16 + lo16;
            size_t nbase = (size_t)tile * 16;
#pragma unroll
            for (int r = 0; r < 4; ++r) {
                int nr = hi4 * 4 + r;
                A_[(nbase + nr) * 64 + o] = (unsigned short)f2bf(fmaxf(acc[r] + bo, 0.0f));
            }
            __syncthreads();   // hlb reused next tile
        }
        grid_barrier(bar, bgrp, xcd);

        // ---- phase GX: B_ = A_ + gather_expander(A_)  (last layer: fused pool) ----
        const uint4* yb = (const uint4*)A_;
        for (int tile = blockIdx.x; tile < NTILE; tile += GRID_MEGA) {
            int nbase = tile * 16;
            int node = nbase + g16;
            int beg = begX[node], end = endX[node];
            int cnt = end - beg;
            int ch = (cnt - half + 1) >> 1;
            const unsigned short* cp = col + beg + half;
            float a[8];
            if (half == 0) {
                uint4 v = yb[(size_t)node * 8 + ln8];
                a[0] = bflo(v.x); a[1] = bfhi(v.x); a[2] = bflo(v.y); a[3] = bfhi(v.y);
                a[4] = bflo(v.z); a[5] = bfhi(v.z); a[6] = bflo(v.w); a[7] = bfhi(v.w);
            } else {
#pragma unroll
                for (int i = 0; i < 8; ++i) a[i] = 0.0f;
            }
            gather_rows(yb, cp, ch, ln8, a);
#pragma unroll
            for (int j = 0; j < 8; ++j) a[j] += __shfl_xor(a[j], 8);
            if (l < NUM_LAYERS - 1) {
                if (half == 0) {
                    uint4 o;
                    o.x = f2bf(a[0]) | (f2bf(a[1]) << 16);
                    o.y = f2bf(a[2]) | (f2bf(a[3]) << 16);
                    o.z = f2bf(a[4]) | (f2bf(a[5]) << 16);
                    o.w = f2bf(a[6]) | (f2bf(a[7]) << 16);
                    ((uint4*)B_)[(size_t)node * 8 + ln8] = o;
                }
            } else {
                if (half == 0) {
                    float4* sp = (float4*)(sacc + g16 * 64 + ln8 * 8);
                    sp[0] = make_float4(a[0], a[1], a[2], a[3]);
                    sp[1] = make_float4(a[4], a[5], a[6], a[7]);
                }
                __syncthreads();
                if (t < 64) {   // per-graph run-length reduce, <=2-3 atomics per col
                    int gprev = batch[nbase];
                    float pacc = 0.0f;
                    for (int r = 0; r < 16; ++r) {
                        int g = batch[nbase + r];
                        float v = sacc[r * 64 + t];
                        if (g != gprev) {
                            atomicAdd(&out[(size_t)gprev * D + t], pacc);
                            pacc = 0.0f;
                            gprev = g;
                        }
                        pacc += v;
                    }
                    atomicAdd(&out[(size_t)gprev * D + t], pacc);
                }
                __syncthreads();   // sacc reused next tile
            }
        }
        if (l < NUM_LAYERS - 1) grid_barrier(bar, bgrp, xcd);
    }
}

// ---------- host ----------
extern "C" void kernel_launch(void* const* d_in, const int* in_sizes, int n_in,
                              void* d_out, int out_size, void* d_ws, size_t ws_size,
                              hipStream_t stream) {
    const float* x_in  = (const float*)d_in[0];
    const int*   ei    = (const int*)d_in[1];
    const int*   eei   = (const int*)d_in[2];
    const int*   batch = (const int*)d_in[3];
    const float* Ws    = (const float*)d_in[4];
    const float* bs    = (const float*)d_in[5];
    float* out = (float*)d_out;

    unsigned short* A = (unsigned short*)d_ws;          // y (bf16) [N*D]
    unsigned short* B = A + (size_t)N_NODES * D;        // x / x' (bf16)
    unsigned short* colAll = B + (size_t)N_NODES * D;   // u16 col [NBUCK*CAP] (holed CSR)
    unsigned* pairs = (unsigned*)(colAll + (size_t)NBUCK * CAP);  // u32 [NBUCK*CAP]
    int* p = (int*)(pairs + (size_t)NBUCK * CAP);
    int* begA = p;          p += N_ALL;
    int* endA = p;          p += N_ALL;
    int* cursor = p;        p += NBUCK;
    int* bar = p;           p += 32;

    const int* e_src = ei;
    const int* e_dst = ei + N_EDGES;
    const int* x_src = eei;
    const int* x_dst = eei + N_EDGES;

    dim3 blk(256);

    // input fp32 -> bf16 (into B); init cursors, pooled out, barrier state
    const int cgrid = (N_NODES * D / 8 + 255) / 256;   // 1563
    x_to_bf16<<<cgrid, blk, 0, stream>>>((const float4*)x_in, (uint4*)B, cursor, out, bar);

    // CSR build: 2 kernels (fixed-cap buckets)
    bin_scatter<<<NCHUNK, blk, 0, stream>>>(e_src, e_dst, x_src, x_dst, cursor, pairs);
    bucket_place<<<NBUCK, blk, 0, stream>>>(pairs, cursor, begA, endA, colAll);

    // all 4 layers + pool: ONE persistent kernel, leader-flush grid barriers
    gin_mega<<<dim3(GRID_MEGA), blk, 0, stream>>>(A, B, begA, endA, colAll,
                                                  Ws, bs, batch, out, bar);
}

// Round 10
// 329.775 us; speedup vs baseline: 7.9688x; 5.5964x over previous
//
#include <hip/hip_runtime.h>

#define N_NODES 50000
#define N_EDGES 800000
#define D 64
#define NUM_LAYERS 4
#define NUM_GRAPHS 128
#define N_ALL (2 * N_NODES)
#define E_ALL (2 * N_EDGES)
#define BSHIFT 9
#define NBUCK ((N_ALL + 511) / 512)     // 196 buckets of 512 dst ids
#define CHUNK 3072                      // edges per bin_scatter block (12/thread)
#define NCHUNK ((E_ALL + CHUNK - 1) / CHUNK)  // 521
#define CAP 16384                       // fixed slots per bucket (max ~8.6k + align pad ~3.6k)

typedef __attribute__((ext_vector_type(8))) short bf16x8;   // 8 bf16 (4 VGPRs)
typedef __attribute__((ext_vector_type(4))) float f32x4;    // MFMA accumulator

// ---------- bf16 helpers (RNE pack, shift unpack) ----------
__device__ __forceinline__ unsigned f2bf(float f) {
    unsigned u = __float_as_uint(f);
    return (u + 0x7FFFu + ((u >> 16) & 1u)) >> 16;
}
__device__ __forceinline__ float bflo(unsigned p) { return __uint_as_float(p << 16); }
__device__ __forceinline__ float bfhi(unsigned p) { return __uint_as_float(p & 0xFFFF0000u); }
__device__ __forceinline__ void acc8(float* a, uint4 v) {
    a[0] += bflo(v.x); a[1] += bfhi(v.x);
    a[2] += bflo(v.y); a[3] += bfhi(v.y);
    a[4] += bflo(v.z); a[5] += bfhi(v.z);
    a[6] += bflo(v.w); a[7] += bfhi(v.w);
}

// ---------- pre-pass: x fp32 -> bf16; init bucket cursors; zero pooled output ----------
__global__ __launch_bounds__(256) void x_to_bf16(const float4* __restrict__ xf,
                                                 uint4* __restrict__ xb,
                                                 int* __restrict__ cursor,
                                                 float* __restrict__ out) {
    int t = threadIdx.x;
    if (blockIdx.x == 0 && t < NBUCK) cursor[t] = t * CAP;
    if (blockIdx.x == 1)
        for (int j = t; j < NUM_GRAPHS * D; j += 256) out[j] = 0.0f;
    int idx = blockIdx.x * 256 + t;          // one uint4 (8 bf16) per thread
    if (idx < N_NODES * D / 8) {
        float4 v0 = xf[(size_t)idx * 2];
        float4 v1 = xf[(size_t)idx * 2 + 1];
        uint4 o;
        o.x = f2bf(v0.x) | (f2bf(v0.y) << 16);
        o.y = f2bf(v0.z) | (f2bf(v0.w) << 16);
        o.z = f2bf(v1.x) | (f2bf(v1.y) << 16);
        o.w = f2bf(v1.z) | (f2bf(v1.w) << 16);
        xb[idx] = o;
    }
}

// ---------- pass 1: bin u32 pairs (d_low9<<16 | src16) into fixed-cap bucket regions ----------
__global__ __launch_bounds__(256) void bin_scatter(const int* __restrict__ sR,
                                                   const int* __restrict__ dR,
                                                   const int* __restrict__ sX,
                                                   const int* __restrict__ dX,
                                                   int* __restrict__ cursor,
                                                   unsigned* __restrict__ pairs) {
    __shared__ unsigned lpair[CHUNK];
    __shared__ unsigned char lbuck[CHUNK];
    __shared__ int lcnt[NBUCK];
    __shared__ int lbase[NBUCK];
    __shared__ int gbase[NBUCK];
    __shared__ int sc[256];
    __shared__ int tot;
    int t = threadIdx.x;
    for (int j = t; j < NBUCK; j += 256) lcnt[j] = 0;
    __syncthreads();

    int base = blockIdx.x * CHUNK;
    unsigned myp[12];
    int myr[12], myb[12];
#pragma unroll
    for (int i = 0; i < 12; ++i) {
        int e = base + i * 256 + t;
        if (e < E_ALL) {
            bool isR = (e < N_EDGES);
            int d = isR ? dR[e] : (N_NODES + dX[e - N_EDGES]);
            int s = isR ? sR[e] : sX[e - N_EDGES];
            myp[i] = ((unsigned)(d & 511) << 16) | (unsigned)s;
            myb[i] = d >> BSHIFT;
            myr[i] = atomicAdd(&lcnt[myb[i]], 1);
        }
    }
    __syncthreads();

    int v = (t < NBUCK) ? lcnt[t] : 0;
    sc[t] = v;
    __syncthreads();
    for (int off = 1; off < 256; off <<= 1) {
        int tv = (t >= off) ? sc[t - off] : 0;
        __syncthreads();
        sc[t] += tv;
        __syncthreads();
    }
    if (t < NBUCK) {
        lbase[t] = sc[t] - v;
        if (v > 0) gbase[t] = atomicAdd(&cursor[t], v);
    }
    if (t == NBUCK - 1) tot = sc[t];
    __syncthreads();

#pragma unroll
    for (int i = 0; i < 12; ++i) {
        int e = base + i * 256 + t;
        if (e < E_ALL) {
            int p = lbase[myb[i]] + myr[i];
            lpair[p] = myp[i];
            lbuck[p] = (unsigned char)myb[i];
        }
    }
    __syncthreads();

    int total = tot;
    for (int j = t; j < total; j += 256) {
        int b = lbuck[j];
        pairs[(size_t)gbase[b] + (j - lbase[b])] = lpair[j];
    }
}

// ---------- pass 2: per bucket -- degrees in LDS, 16B-ALIGNED node starts, place col ----------
// Each node's edge run starts at a multiple of 8 entries (16 B) so gathers can read col
// indices with aligned uint4 loads. Holes contain garbage; gathers read only [beg, beg+deg).
__global__ __launch_bounds__(256) void bucket_place(const unsigned* __restrict__ pairs,
                                                    const int* __restrict__ cursor,
                                                    int* __restrict__ begA,
                                                    int* __restrict__ endA,
                                                    unsigned short* __restrict__ col) {
    __shared__ unsigned short scol[CAP];
    __shared__ int ldeg[512];
    __shared__ int lcur[512];
    __shared__ int s1[256];
    __shared__ int tot;
    int b = blockIdx.x;
    int d0 = b << BSHIFT;
    int nd = min(512, N_ALL - d0);
    int t = threadIdx.x;
    int base = b * CAP;
    int cnt = cursor[b] - base;
    ldeg[t] = 0; ldeg[t + 256] = 0;
    __syncthreads();
    for (int i = t; i < cnt; i += 256) {
        int dl = pairs[(size_t)base + i] >> 16;
        atomicAdd(&ldeg[dl], 1);
    }
    __syncthreads();
    int v0 = ldeg[2 * t], v1 = ldeg[2 * t + 1];
    int c0 = (v0 + 7) & ~7, c1 = (v1 + 7) & ~7;      // 8-entry aligned allocations
    int pv = c0 + c1;
    s1[t] = pv;
    __syncthreads();
    for (int off = 1; off < 256; off <<= 1) {
        int tv = (t >= off) ? s1[t - off] : 0;
        __syncthreads();
        s1[t] += tv;
        __syncthreads();
    }
    int before = s1[t] - pv;
    lcur[2 * t] = before;
    lcur[2 * t + 1] = before + c0;
    if (2 * t < nd) {
        begA[d0 + 2 * t] = base + before;
        endA[d0 + 2 * t] = base + before + v0;
    }
    if (2 * t + 1 < nd) {
        begA[d0 + 2 * t + 1] = base + before + c0;
        endA[d0 + 2 * t + 1] = base + before + c0 + v1;
    }
    if (t == 255) tot = s1[t];
    __syncthreads();
    for (int i = t; i < cnt; i += 256) {
        unsigned pr = pairs[(size_t)base + i];
        int dl = pr >> 16;
        int p = atomicAdd(&lcur[dl], 1);
        scol[p] = (unsigned short)(pr & 0xFFFFu);
    }
    __syncthreads();
    int used = tot;                                   // aligned extent (holes included)
    for (int i = t; i < used; i += 256) col[base + i] = scol[i];
}

// ---------- gather helper v2: contiguous 8-edge chunks per half, uint4 col loads ----------
// colbase is 16B-aligned (node starts are 8-entry aligned). half h processes edge blocks
// [e0, e0+8) for e0 = h*8, h*8+16, ... Col indices for 8 edges arrive in ONE uint4.
__device__ __forceinline__ void gather_rows(const uint4* __restrict__ xb,
                                            const unsigned short* __restrict__ colbase,
                                            int cnt, int half, int ln8, float* a) {
    for (int e0 = half * 8; e0 < cnt; e0 += 16) {
        uint4 cv = *(const uint4*)(colbase + e0);   // aligned; may cover pad (values unused)
        int rem = cnt - e0;
        int s0 = cv.x & 0xFFFF, s1 = cv.x >> 16;
        int s2 = cv.y & 0xFFFF, s3 = cv.y >> 16;
        int s4 = cv.z & 0xFFFF, s5 = cv.z >> 16;
        int s6 = cv.w & 0xFFFF, s7 = cv.w >> 16;
        if (rem >= 8) {
            uint4 v0 = xb[(size_t)s0 * 8 + ln8];
            uint4 v1 = xb[(size_t)s1 * 8 + ln8];
            uint4 v2 = xb[(size_t)s2 * 8 + ln8];
            uint4 v3 = xb[(size_t)s3 * 8 + ln8];
            uint4 v4 = xb[(size_t)s4 * 8 + ln8];
            uint4 v5 = xb[(size_t)s5 * 8 + ln8];
            uint4 v6 = xb[(size_t)s6 * 8 + ln8];
            uint4 v7 = xb[(size_t)s7 * 8 + ln8];
            acc8(a, v0); acc8(a, v1); acc8(a, v2); acc8(a, v3);
            acc8(a, v4); acc8(a, v5); acc8(a, v6); acc8(a, v7);
        } else {                                    // tail: rem in 1..7, static ladder
            if (rem > 0) acc8(a, xb[(size_t)s0 * 8 + ln8]);
            if (rem > 1) acc8(a, xb[(size_t)s1 * 8 + ln8]);
            if (rem > 2) acc8(a, xb[(size_t)s2 * 8 + ln8]);
            if (rem > 3) acc8(a, xb[(size_t)s3 * 8 + ln8]);
            if (rem > 4) acc8(a, xb[(size_t)s4 * 8 + ln8]);
            if (rem > 5) acc8(a, xb[(size_t)s5 * 8 + ln8]);
            if (rem > 6) acc8(a, xb[(size_t)s6 * 8 + ln8]);
        }
    }
}

// ---------- split-edge bf16 gather (expander layers 0..2) ----------
__global__ __launch_bounds__(256, 8) void gather_bf16(const uint4* __restrict__ xb,
                                                      uint4* __restrict__ ob,
                                                      const int* __restrict__ begA,
                                                      const int* __restrict__ endA,
                                                      const unsigned short* __restrict__ col) {
    int t = threadIdx.x;
    int grp = t >> 4;
    int half = (t >> 3) & 1;
    int ln8 = t & 7;
    int node = blockIdx.x * 16 + grp;   // grid exactly covers 50000
    int beg = begA[node], end = endA[node];
    int cnt = end - beg;
    const unsigned short* colbase = col + beg;   // 16B aligned
    float a[8];
    if (half == 0) {
        uint4 v = xb[(size_t)node * 8 + ln8];
        a[0] = bflo(v.x); a[1] = bfhi(v.x); a[2] = bflo(v.y); a[3] = bfhi(v.y);
        a[4] = bflo(v.z); a[5] = bfhi(v.z); a[6] = bflo(v.w); a[7] = bfhi(v.w);
    } else {
#pragma unroll
        for (int i = 0; i < 8; ++i) a[i] = 0.0f;
    }
    gather_rows(xb, colbase, cnt, half, ln8, a);
#pragma unroll
    for (int j = 0; j < 8; ++j) a[j] += __shfl_xor(a[j], 8);
    if (half == 0) {
        uint4 o;
        o.x = f2bf(a[0]) | (f2bf(a[1]) << 16);
        o.y = f2bf(a[2]) | (f2bf(a[3]) << 16);
        o.z = f2bf(a[4]) | (f2bf(a[5]) << 16);
        o.w = f2bf(a[6]) | (f2bf(a[7]) << 16);
        ob[(size_t)node * 8 + ln8] = o;
    }
}

// ---------- last expander gather fused with graph pooling (batch is sorted) ----------
__global__ __launch_bounds__(256, 8) void gather_pool_bf16(const uint4* __restrict__ xb,
                                                           const int* __restrict__ begA,
                                                           const int* __restrict__ endA,
                                                           const unsigned short* __restrict__ col,
                                                           const int* __restrict__ batch,
                                                           float* __restrict__ out) {
    __shared__ float sacc[16 * 64];
    int t = threadIdx.x;
    int grp = t >> 4;
    int half = (t >> 3) & 1;
    int ln8 = t & 7;
    int nbase = blockIdx.x * 16;
    int node = nbase + grp;
    int beg = begA[node], end = endA[node];
    int cnt = end - beg;
    const unsigned short* colbase = col + beg;
    float a[8];
    if (half == 0) {
        uint4 v = xb[(size_t)node * 8 + ln8];
        a[0] = bflo(v.x); a[1] = bfhi(v.x); a[2] = bflo(v.y); a[3] = bfhi(v.y);
        a[4] = bflo(v.z); a[5] = bfhi(v.z); a[6] = bflo(v.w); a[7] = bfhi(v.w);
    } else {
#pragma unroll
        for (int i = 0; i < 8; ++i) a[i] = 0.0f;
    }
    gather_rows(xb, colbase, cnt, half, ln8, a);
#pragma unroll
    for (int j = 0; j < 8; ++j) a[j] += __shfl_xor(a[j], 8);
    if (half == 0) {
        float4* sp = (float4*)(sacc + grp * 64 + ln8 * 8);
        sp[0] = make_float4(a[0], a[1], a[2], a[3]);
        sp[1] = make_float4(a[4], a[5], a[6], a[7]);
    }
    __syncthreads();

    // per-graph run-length reduce over the block's 16 rows, then atomics (<=2-3 per col)
    if (t < 64) {
        int gprev = batch[nbase];
        float acc = 0.0f;
        for (int r = 0; r < 16; ++r) {
            int g = batch[nbase + r];
            float v = sacc[r * 64 + t];
            if (g != gprev) {
                atomicAdd(&out[(size_t)gprev * D + t], acc);
                acc = 0.0f;
                gprev = g;
            }
            acc += v;
        }
        atomicAdd(&out[(size_t)gprev * D + t], acc);
    }
}

// ---------- fused: y = relu( (x + gather(x)) @ W^T + b ) -- MFMA MLP ----------
__global__ __launch_bounds__(256, 6) void gather_linear(const uint4* __restrict__ xb,
                                                        unsigned short* __restrict__ y,
                                                        const int* __restrict__ begA,
                                                        const int* __restrict__ endA,
                                                        const unsigned short* __restrict__ col,
                                                        const float* __restrict__ W,
                                                        const float* __restrict__ b) {
    __shared__ __align__(16) unsigned short hlb[16 * 72];       // h bf16, stride 72 (conflict-free)
    __shared__ __align__(16) unsigned short Wb[4 * 2 * 64 * 8]; // B-frags [wave][kk][lane][8]
    int t = threadIdx.x;
    int wv = t >> 6, lane = t & 63;
    int lo16 = lane & 15, hi4 = lane >> 4;

    // ---- B-fragment precompute: Wb[wv][kk][lane][j] = W[wv*16+lo16][kk*32+hi4*8+j] ----
    {
        const float* wp = W + (wv * 16 + lo16) * 64 + hi4 * 8;
#pragma unroll
        for (int kk = 0; kk < 2; ++kk) {
            float4 w0 = *(const float4*)(wp + kk * 32);
            float4 w1 = *(const float4*)(wp + kk * 32 + 4);
            uint4 pk;
            pk.x = f2bf(w0.x) | (f2bf(w0.y) << 16);
            pk.y = f2bf(w0.z) | (f2bf(w0.w) << 16);
            pk.z = f2bf(w1.x) | (f2bf(w1.y) << 16);
            pk.w = f2bf(w1.z) | (f2bf(w1.w) << 16);
            *(uint4*)&Wb[((wv * 2 + kk) * 64 + lane) * 8] = pk;
        }
    }

    // ---- gather phase: h = x + sum_{j in N} x_j ----
    int grp = t >> 4;
    int half = (t >> 3) & 1;
    int ln8 = t & 7;
    int node = blockIdx.x * 16 + grp;   // grid exactly covers 50000
    int beg = begA[node], end = endA[node];
    int cnt = end - beg;
    const unsigned short* colbase = col + beg;
    float a[8];
    if (half == 0) {
        uint4 v = xb[(size_t)node * 8 + ln8];
        a[0] = bflo(v.x); a[1] = bfhi(v.x); a[2] = bflo(v.y); a[3] = bfhi(v.y);
        a[4] = bflo(v.z); a[5] = bfhi(v.z); a[6] = bflo(v.w); a[7] = bfhi(v.w);
    } else {
#pragma unroll
        for (int i = 0; i < 8; ++i) a[i] = 0.0f;
    }
    gather_rows(xb, colbase, cnt, half, ln8, a);
#pragma unroll
    for (int j = 0; j < 8; ++j) a[j] += __shfl_xor(a[j], 8);
    if (half == 0) {
        uint4 o4;
        o4.x = f2bf(a[0]) | (f2bf(a[1]) << 16);
        o4.y = f2bf(a[2]) | (f2bf(a[3]) << 16);
        o4.z = f2bf(a[4]) | (f2bf(a[5]) << 16);
        o4.w = f2bf(a[6]) | (f2bf(a[7]) << 16);
        *(uint4*)&hlb[grp * 72 + ln8 * 8] = o4;   // 16B, conflict-free (stride 72)
    }
    __syncthreads();

    // ---- MFMA MLP: 2 x mfma_f32_16x16x32_bf16 per wave ----
    f32x4 acc = {0.0f, 0.0f, 0.0f, 0.0f};
    bf16x8 a0 = *(const bf16x8*)&hlb[lo16 * 72 + hi4 * 8];
    bf16x8 a1 = *(const bf16x8*)&hlb[lo16 * 72 + 32 + hi4 * 8];
    bf16x8 b0 = *(const bf16x8*)&Wb[((wv * 2 + 0) * 64 + lane) * 8];
    bf16x8 b1 = *(const bf16x8*)&Wb[((wv * 2 + 1) * 64 + lane) * 8];
    acc = __builtin_amdgcn_mfma_f32_16x16x32_bf16(a0, b0, acc, 0, 0, 0);
    acc = __builtin_amdgcn_mfma_f32_16x16x32_bf16(a1, b1, acc, 0, 0, 0);

    int o = wv * 16 + lo16;
    float bo = b[o];
    size_t nb = (size_t)blockIdx.x * 16;
#pragma unroll
    for (int r = 0; r < 4; ++r) {
        int nr = hi4 * 4 + r;
        y[(nb + nr) * 64 + o] = (unsigned short)f2bf(fmaxf(acc[r] + bo, 0.0f));
    }
}

// ---------- host ----------
extern "C" void kernel_launch(void* const* d_in, const int* in_sizes, int n_in,
                              void* d_out, int out_size, void* d_ws, size_t ws_size,
                              hipStream_t stream) {
    const float* x_in  = (const float*)d_in[0];
    const int*   ei    = (const int*)d_in[1];
    const int*   eei   = (const int*)d_in[2];
    const int*   batch = (const int*)d_in[3];
    const float* Ws    = (const float*)d_in[4];
    const float* bs    = (const float*)d_in[5];
    float* out = (float*)d_out;

    unsigned short* A = (unsigned short*)d_ws;          // y (bf16) [N*D]
    unsigned short* B = A + (size_t)N_NODES * D;        // x / x' (bf16)
    unsigned short* colAll = B + (size_t)N_NODES * D;   // u16 col [NBUCK*CAP] (holed, aligned)
    unsigned* pairs = (unsigned*)(colAll + (size_t)NBUCK * CAP);  // u32 [NBUCK*CAP]
    int* p = (int*)(pairs + (size_t)NBUCK * CAP);
    int* begA = p;          p += N_ALL;
    int* endA = p;          p += N_ALL;
    int* cursor = p;        p += NBUCK;

    const int* e_src = ei;
    const int* e_dst = ei + N_EDGES;
    const int* x_src = eei;
    const int* x_dst = eei + N_EDGES;

    dim3 blk(256);

    // input fp32 -> bf16 (into B); init bucket cursors; zero pooled out
    const int cgrid = (N_NODES * D / 8 + 255) / 256;   // 1563
    x_to_bf16<<<cgrid, blk, 0, stream>>>((const float4*)x_in, (uint4*)B, cursor, out);

    // CSR build: 2 kernels (fixed-cap buckets, 16B-aligned node runs)
    bin_scatter<<<NCHUNK, blk, 0, stream>>>(e_src, e_dst, x_src, x_dst, cursor, pairs);
    bucket_place<<<NBUCK, blk, 0, stream>>>(pairs, cursor, begA, endA, colAll);

    const int lgrid = N_NODES / 16;            // 3125, exact

    // 4 layers; final expander gather fused with pooling
    for (int i = 0; i < NUM_LAYERS; ++i) {
        gather_linear<<<lgrid, blk, 0, stream>>>((const uint4*)B, A,
                                                 begA, endA, colAll,
                                                 Ws + (size_t)i * D * D,
                                                 bs + (size_t)i * D);
        if (i < NUM_LAYERS - 1)
            gather_bf16<<<lgrid, blk, 0, stream>>>((const uint4*)A, (uint4*)B,
                                                   begA + N_NODES, endA + N_NODES, colAll);
        else
            gather_pool_bf16<<<lgrid, blk, 0, stream>>>((const uint4*)A,
                                                        begA + N_NODES, endA + N_NODES,
                                                        colAll, batch, out);
    }
}

// Round 11
// 255.443 us; speedup vs baseline: 10.2877x; 1.2910x over previous
//
#include <hip/hip_runtime.h>

#define N_NODES 50000
#define N_EDGES 800000
#define D 64
#define NUM_LAYERS 4
#define NUM_GRAPHS 128
#define N_ALL (2 * N_NODES)
#define E_ALL (2 * N_EDGES)
#define BSHIFT 9
#define NBUCK ((N_ALL + 511) / 512)     // 196 buckets of 512 dst ids
#define CHUNK 3072                      // edges per bin_scatter block (12/thread)
#define NCHUNK ((E_ALL + CHUNK - 1) / CHUNK)  // 521
#define CAP 12288                       // fixed slots per bucket (expected max ~8.6k)

typedef __attribute__((ext_vector_type(8))) short bf16x8;   // 8 bf16 (4 VGPRs)
typedef __attribute__((ext_vector_type(4))) float f32x4;    // MFMA accumulator

// ---------- bf16 helpers (RNE pack, shift unpack) ----------
__device__ __forceinline__ unsigned f2bf(float f) {
    unsigned u = __float_as_uint(f);
    return (u + 0x7FFFu + ((u >> 16) & 1u)) >> 16;
}
__device__ __forceinline__ float bflo(unsigned p) { return __uint_as_float(p << 16); }
__device__ __forceinline__ float bfhi(unsigned p) { return __uint_as_float(p & 0xFFFF0000u); }
__device__ __forceinline__ void acc8(float* a, uint4 v) {
    a[0] += bflo(v.x); a[1] += bfhi(v.x);
    a[2] += bflo(v.y); a[3] += bfhi(v.y);
    a[4] += bflo(v.z); a[5] += bfhi(v.z);
    a[6] += bflo(v.w); a[7] += bfhi(v.w);
}

// ---------- pre-pass: x fp32 -> bf16; init bucket cursors; zero pooled output ----------
__global__ __launch_bounds__(256) void x_to_bf16(const float4* __restrict__ xf,
                                                 uint4* __restrict__ xb,
                                                 int* __restrict__ cursor,
                                                 float* __restrict__ out) {
    int t = threadIdx.x;
    if (blockIdx.x == 0 && t < NBUCK) cursor[t] = t * CAP;
    if (blockIdx.x == 1)
        for (int j = t; j < NUM_GRAPHS * D; j += 256) out[j] = 0.0f;
    int idx = blockIdx.x * 256 + t;          // one uint4 (8 bf16) per thread
    if (idx < N_NODES * D / 8) {
        float4 v0 = xf[(size_t)idx * 2];
        float4 v1 = xf[(size_t)idx * 2 + 1];
        uint4 o;
        o.x = f2bf(v0.x) | (f2bf(v0.y) << 16);
        o.y = f2bf(v0.z) | (f2bf(v0.w) << 16);
        o.z = f2bf(v1.x) | (f2bf(v1.y) << 16);
        o.w = f2bf(v1.z) | (f2bf(v1.w) << 16);
        xb[idx] = o;
    }
}

// ---------- pass 1: bin u32 pairs (d_low9<<16 | src16) into fixed-cap bucket regions ----------
__global__ __launch_bounds__(256) void bin_scatter(const int* __restrict__ sR,
                                                   const int* __restrict__ dR,
                                                   const int* __restrict__ sX,
                                                   const int* __restrict__ dX,
                                                   int* __restrict__ cursor,
                                                   unsigned* __restrict__ pairs) {
    __shared__ unsigned lpair[CHUNK];
    __shared__ unsigned char lbuck[CHUNK];
    __shared__ int lcnt[NBUCK];
    __shared__ int lbase[NBUCK];
    __shared__ int gbase[NBUCK];
    __shared__ int sc[256];
    __shared__ int tot;
    int t = threadIdx.x;
    for (int j = t; j < NBUCK; j += 256) lcnt[j] = 0;
    __syncthreads();

    int base = blockIdx.x * CHUNK;
    unsigned myp[12];
    int myr[12], myb[12];
#pragma unroll
    for (int i = 0; i < 12; ++i) {
        int e = base + i * 256 + t;
        if (e < E_ALL) {
            bool isR = (e < N_EDGES);
            int d = isR ? dR[e] : (N_NODES + dX[e - N_EDGES]);
            int s = isR ? sR[e] : sX[e - N_EDGES];
            myp[i] = ((unsigned)(d & 511) << 16) | (unsigned)s;
            myb[i] = d >> BSHIFT;
            myr[i] = atomicAdd(&lcnt[myb[i]], 1);
        }
    }
    __syncthreads();

    int v = (t < NBUCK) ? lcnt[t] : 0;
    sc[t] = v;
    __syncthreads();
    for (int off = 1; off < 256; off <<= 1) {
        int tv = (t >= off) ? sc[t - off] : 0;
        __syncthreads();
        sc[t] += tv;
        __syncthreads();
    }
    if (t < NBUCK) {
        lbase[t] = sc[t] - v;
        if (v > 0) gbase[t] = atomicAdd(&cursor[t], v);
    }
    if (t == NBUCK - 1) tot = sc[t];
    __syncthreads();

#pragma unroll
    for (int i = 0; i < 12; ++i) {
        int e = base + i * 256 + t;
        if (e < E_ALL) {
            int p = lbase[myb[i]] + myr[i];
            lpair[p] = myp[i];
            lbuck[p] = (unsigned char)myb[i];
        }
    }
    __syncthreads();

    int total = tot;
    for (int j = t; j < total; j += 256) {
        int b = lbuck[j];
        pairs[(size_t)gbase[b] + (j - lbase[b])] = lpair[j];
    }
}

// ---------- pass 2: per bucket -- degrees in LDS, beg/end arrays, place col ----------
__global__ __launch_bounds__(256) void bucket_place(const unsigned* __restrict__ pairs,
                                                    const int* __restrict__ cursor,
                                                    int* __restrict__ begA,
                                                    int* __restrict__ endA,
                                                    unsigned short* __restrict__ col) {
    __shared__ unsigned short scol[CAP];
    __shared__ int ldeg[512];
    __shared__ int lcur[512];
    __shared__ int s1[256];
    int b = blockIdx.x;
    int d0 = b << BSHIFT;
    int nd = min(512, N_ALL - d0);
    int t = threadIdx.x;
    int base = b * CAP;
    int cnt = cursor[b] - base;
    ldeg[t] = 0; ldeg[t + 256] = 0;
    __syncthreads();
    for (int i = t; i < cnt; i += 256) {
        int dl = pairs[(size_t)base + i] >> 16;
        atomicAdd(&ldeg[dl], 1);
    }
    __syncthreads();
    int v0 = ldeg[2 * t], v1 = ldeg[2 * t + 1];
    int pv = v0 + v1;
    s1[t] = pv;
    __syncthreads();
    for (int off = 1; off < 256; off <<= 1) {
        int tv = (t >= off) ? s1[t - off] : 0;
        __syncthreads();
        s1[t] += tv;
        __syncthreads();
    }
    int before = s1[t] - pv;
    lcur[2 * t] = before;
    lcur[2 * t + 1] = before + v0;
    if (2 * t < nd) {
        begA[d0 + 2 * t] = base + before;
        endA[d0 + 2 * t] = base + before + v0;
    }
    if (2 * t + 1 < nd) {
        begA[d0 + 2 * t + 1] = base + before + v0;
        endA[d0 + 2 * t + 1] = base + before + v0 + v1;
    }
    __syncthreads();
    for (int i = t; i < cnt; i += 256) {
        unsigned pr = pairs[(size_t)base + i];
        int dl = pr >> 16;
        int p = atomicAdd(&lcur[dl], 1);
        scol[p] = (unsigned short)(pr & 0xFFFFu);
    }
    __syncthreads();
    for (int i = t; i < cnt; i += 256) col[base + i] = scol[i];
}

// ---------- shared gather helper: a[8] += sum of neighbor rows (split-edge, unroll 8) ----------
// Stride-2 interleaved halves; independent scalar col loads let the compiler keep
// ~16 loads in flight (R10 lesson: chunked/dependent col loads regressed 29%).
__device__ __forceinline__ void gather_rows(const uint4* __restrict__ xb,
                                            const unsigned short* __restrict__ cp,
                                            int ch, int ln8, float* a) {
    int i = 0;
    for (; i + 8 <= ch; i += 8) {
        int s0 = cp[2 * i],      s1 = cp[2 * i + 2],  s2 = cp[2 * i + 4],  s3 = cp[2 * i + 6];
        int s4 = cp[2 * i + 8],  s5 = cp[2 * i + 10], s6 = cp[2 * i + 12], s7 = cp[2 * i + 14];
        uint4 v0 = xb[(size_t)s0 * 8 + ln8];
        uint4 v1 = xb[(size_t)s1 * 8 + ln8];
        uint4 v2 = xb[(size_t)s2 * 8 + ln8];
        uint4 v3 = xb[(size_t)s3 * 8 + ln8];
        uint4 v4 = xb[(size_t)s4 * 8 + ln8];
        uint4 v5 = xb[(size_t)s5 * 8 + ln8];
        uint4 v6 = xb[(size_t)s6 * 8 + ln8];
        uint4 v7 = xb[(size_t)s7 * 8 + ln8];
        acc8(a, v0); acc8(a, v1); acc8(a, v2); acc8(a, v3);
        acc8(a, v4); acc8(a, v5); acc8(a, v6); acc8(a, v7);
    }
    for (; i + 4 <= ch; i += 4) {
        int s0 = cp[2 * i], s1 = cp[2 * i + 2], s2 = cp[2 * i + 4], s3 = cp[2 * i + 6];
        uint4 v0 = xb[(size_t)s0 * 8 + ln8];
        uint4 v1 = xb[(size_t)s1 * 8 + ln8];
        uint4 v2 = xb[(size_t)s2 * 8 + ln8];
        uint4 v3 = xb[(size_t)s3 * 8 + ln8];
        acc8(a, v0); acc8(a, v1); acc8(a, v2); acc8(a, v3);
    }
    for (; i < ch; ++i) acc8(a, xb[(size_t)cp[2 * i] * 8 + ln8]);
}

// ---------- split-edge bf16 gather (expander layers 0..2) ----------
__global__ __launch_bounds__(256, 8) void gather_bf16(const uint4* __restrict__ xb,
                                                      uint4* __restrict__ ob,
                                                      const int* __restrict__ begA,
                                                      const int* __restrict__ endA,
                                                      const unsigned short* __restrict__ col) {
    int t = threadIdx.x;
    int grp = t >> 4;
    int half = (t >> 3) & 1;
    int ln8 = t & 7;
    int node = blockIdx.x * 16 + grp;   // grid exactly covers 50000
    int beg = begA[node], end = endA[node];
    int cnt = end - beg;
    int ch = (cnt - half + 1) >> 1;
    const unsigned short* cp = col + beg + half;
    float a[8];
    if (half == 0) {
        uint4 v = xb[(size_t)node * 8 + ln8];
        a[0] = bflo(v.x); a[1] = bfhi(v.x); a[2] = bflo(v.y); a[3] = bfhi(v.y);
        a[4] = bflo(v.z); a[5] = bfhi(v.z); a[6] = bflo(v.w); a[7] = bfhi(v.w);
    } else {
#pragma unroll
        for (int i = 0; i < 8; ++i) a[i] = 0.0f;
    }
    gather_rows(xb, cp, ch, ln8, a);
#pragma unroll
    for (int j = 0; j < 8; ++j) a[j] += __shfl_xor(a[j], 8);
    if (half == 0) {
        uint4 o;
        o.x = f2bf(a[0]) | (f2bf(a[1]) << 16);
        o.y = f2bf(a[2]) | (f2bf(a[3]) << 16);
        o.z = f2bf(a[4]) | (f2bf(a[5]) << 16);
        o.w = f2bf(a[6]) | (f2bf(a[7]) << 16);
        ob[(size_t)node * 8 + ln8] = o;
    }
}

// ---------- last expander gather fused with graph pooling (batch is sorted) ----------
__global__ __launch_bounds__(256, 8) void gather_pool_bf16(const uint4* __restrict__ xb,
                                                           const int* __restrict__ begA,
                                                           const int* __restrict__ endA,
                                                           const unsigned short* __restrict__ col,
                                                           const int* __restrict__ batch,
                                                           float* __restrict__ out) {
    __shared__ float sacc[16 * 64];
    int t = threadIdx.x;
    int grp = t >> 4;
    int half = (t >> 3) & 1;
    int ln8 = t & 7;
    int nbase = blockIdx.x * 16;
    int node = nbase + grp;
    int beg = begA[node], end = endA[node];
    int cnt = end - beg;
    int ch = (cnt - half + 1) >> 1;
    const unsigned short* cp = col + beg + half;
    float a[8];
    if (half == 0) {
        uint4 v = xb[(size_t)node * 8 + ln8];
        a[0] = bflo(v.x); a[1] = bfhi(v.x); a[2] = bflo(v.y); a[3] = bfhi(v.y);
        a[4] = bflo(v.z); a[5] = bfhi(v.z); a[6] = bflo(v.w); a[7] = bfhi(v.w);
    } else {
#pragma unroll
        for (int i = 0; i < 8; ++i) a[i] = 0.0f;
    }
    gather_rows(xb, cp, ch, ln8, a);
#pragma unroll
    for (int j = 0; j < 8; ++j) a[j] += __shfl_xor(a[j], 8);
    if (half == 0) {
        float4* sp = (float4*)(sacc + grp * 64 + ln8 * 8);
        sp[0] = make_float4(a[0], a[1], a[2], a[3]);
        sp[1] = make_float4(a[4], a[5], a[6], a[7]);
    }
    __syncthreads();

    // per-graph run-length reduce over the block's 16 rows, then atomics (<=2-3 per col)
    if (t < 64) {
        int gprev = batch[nbase];
        float acc = 0.0f;
        for (int r = 0; r < 16; ++r) {
            int g = batch[nbase + r];
            float v = sacc[r * 64 + t];
            if (g != gprev) {
                atomicAdd(&out[(size_t)gprev * D + t], acc);
                acc = 0.0f;
                gprev = g;
            }
            acc += v;
        }
        atomicAdd(&out[(size_t)gprev * D + t], acc);
    }
}

// ---------- fused: y = relu( (x + gather(x)) @ W^T + b ) -- MFMA MLP ----------
__global__ __launch_bounds__(256, 6) void gather_linear(const uint4* __restrict__ xb,
                                                        unsigned short* __restrict__ y,
                                                        const int* __restrict__ begA,
                                                        const int* __restrict__ endA,
                                                        const unsigned short* __restrict__ col,
                                                        const float* __restrict__ W,
                                                        const float* __restrict__ b) {
    __shared__ __align__(16) unsigned short hlb[16 * 72];       // h bf16, stride 72 (conflict-free)
    __shared__ __align__(16) unsigned short Wb[4 * 2 * 64 * 8]; // B-frags [wave][kk][lane][8]
    int t = threadIdx.x;
    int wv = t >> 6, lane = t & 63;
    int lo16 = lane & 15, hi4 = lane >> 4;

    // ---- B-fragment precompute: Wb[wv][kk][lane][j] = W[wv*16+lo16][kk*32+hi4*8+j] ----
    {
        const float* wp = W + (wv * 16 + lo16) * 64 + hi4 * 8;
#pragma unroll
        for (int kk = 0; kk < 2; ++kk) {
            float4 w0 = *(const float4*)(wp + kk * 32);
            float4 w1 = *(const float4*)(wp + kk * 32 + 4);
            uint4 pk;
            pk.x = f2bf(w0.x) | (f2bf(w0.y) << 16);
            pk.y = f2bf(w0.z) | (f2bf(w0.w) << 16);
            pk.z = f2bf(w1.x) | (f2bf(w1.y) << 16);
            pk.w = f2bf(w1.z) | (f2bf(w1.w) << 16);
            *(uint4*)&Wb[((wv * 2 + kk) * 64 + lane) * 8] = pk;
        }
    }

    // ---- gather phase: h = x + sum_{j in N} x_j ----
    int grp = t >> 4;
    int half = (t >> 3) & 1;
    int ln8 = t & 7;
    int node = blockIdx.x * 16 + grp;   // grid exactly covers 50000
    int beg = begA[node], end = endA[node];
    int cnt = end - beg;
    int ch = (cnt - half + 1) >> 1;
    const unsigned short* cp = col + beg + half;
    float a[8];
    if (half == 0) {
        uint4 v = xb[(size_t)node * 8 + ln8];
        a[0] = bflo(v.x); a[1] = bfhi(v.x); a[2] = bflo(v.y); a[3] = bfhi(v.y);
        a[4] = bflo(v.z); a[5] = bfhi(v.z); a[6] = bflo(v.w); a[7] = bfhi(v.w);
    } else {
#pragma unroll
        for (int i = 0; i < 8; ++i) a[i] = 0.0f;
    }
    gather_rows(xb, cp, ch, ln8, a);
#pragma unroll
    for (int j = 0; j < 8; ++j) a[j] += __shfl_xor(a[j], 8);
    if (half == 0) {
        uint4 o4;
        o4.x = f2bf(a[0]) | (f2bf(a[1]) << 16);
        o4.y = f2bf(a[2]) | (f2bf(a[3]) << 16);
        o4.z = f2bf(a[4]) | (f2bf(a[5]) << 16);
        o4.w = f2bf(a[6]) | (f2bf(a[7]) << 16);
        *(uint4*)&hlb[grp * 72 + ln8 * 8] = o4;   // 16B, conflict-free (stride 72)
    }
    __syncthreads();

    // ---- MFMA MLP: 2 x mfma_f32_16x16x32_bf16 per wave ----
    f32x4 acc = {0.0f, 0.0f, 0.0f, 0.0f};
    bf16x8 a0 = *(const bf16x8*)&hlb[lo16 * 72 + hi4 * 8];
    bf16x8 a1 = *(const bf16x8*)&hlb[lo16 * 72 + 32 + hi4 * 8];
    bf16x8 b0 = *(const bf16x8*)&Wb[((wv * 2 + 0) * 64 + lane) * 8];
    bf16x8 b1 = *(const bf16x8*)&Wb[((wv * 2 + 1) * 64 + lane) * 8];
    acc = __builtin_amdgcn_mfma_f32_16x16x32_bf16(a0, b0, acc, 0, 0, 0);
    acc = __builtin_amdgcn_mfma_f32_16x16x32_bf16(a1, b1, acc, 0, 0, 0);

    int o = wv * 16 + lo16;
    float bo = b[o];
    size_t nbase = (size_t)blockIdx.x * 16;
#pragma unroll
    for (int r = 0; r < 4; ++r) {
        int nr = hi4 * 4 + r;
        y[(nbase + nr) * 64 + o] = (unsigned short)f2bf(fmaxf(acc[r] + bo, 0.0f));
    }
}

// ---------- host ----------
extern "C" void kernel_launch(void* const* d_in, const int* in_sizes, int n_in,
                              void* d_out, int out_size, void* d_ws, size_t ws_size,
                              hipStream_t stream) {
    const float* x_in  = (const float*)d_in[0];
    const int*   ei    = (const int*)d_in[1];
    const int*   eei   = (const int*)d_in[2];
    const int*   batch = (const int*)d_in[3];
    const float* Ws    = (const float*)d_in[4];
    const float* bs    = (const float*)d_in[5];
    float* out = (float*)d_out;

    unsigned short* A = (unsigned short*)d_ws;          // y (bf16) [N*D]
    unsigned short* B = A + (size_t)N_NODES * D;        // x / x' (bf16)
    unsigned short* colAll = B + (size_t)N_NODES * D;   // u16 col [NBUCK*CAP] (holed CSR)
    unsigned* pairs = (unsigned*)(colAll + (size_t)NBUCK * CAP);  // u32 [NBUCK*CAP]
    int* p = (int*)(pairs + (size_t)NBUCK * CAP);
    int* begA = p;          p += N_ALL;
    int* endA = p;          p += N_ALL;
    int* cursor = p;        p += NBUCK;

    const int* e_src = ei;
    const int* e_dst = ei + N_EDGES;
    const int* x_src = eei;
    const int* x_dst = eei + N_EDGES;

    dim3 blk(256);

    // input fp32 -> bf16 (into B); init bucket cursors; zero pooled out
    const int cgrid = (N_NODES * D / 8 + 255) / 256;   // 1563
    x_to_bf16<<<cgrid, blk, 0, stream>>>((const float4*)x_in, (uint4*)B, cursor, out);

    // CSR build: 2 kernels (fixed-cap buckets; no count/scan passes)
    bin_scatter<<<NCHUNK, blk, 0, stream>>>(e_src, e_dst, x_src, x_dst, cursor, pairs);
    bucket_place<<<NBUCK, blk, 0, stream>>>(pairs, cursor, begA, endA, colAll);

    const int lgrid = N_NODES / 16;            // 3125, exact

    // 4 layers; final expander gather fused with pooling
    for (int i = 0; i < NUM_LAYERS; ++i) {
        gather_linear<<<lgrid, blk, 0, stream>>>((const uint4*)B, A,
                                                 begA, endA, colAll,
                                                 Ws + (size_t)i * D * D,
                                                 bs + (size_t)i * D);
        if (i < NUM_LAYERS - 1)
            gather_bf16<<<lgrid, blk, 0, stream>>>((const uint4*)A, (uint4*)B,
                                                   begA + N_NODES, endA + N_NODES, colAll);
        else
            gather_pool_bf16<<<lgrid, blk, 0, stream>>>((const uint4*)A,
                                                        begA + N_NODES, endA + N_NODES,
                                                        colAll, batch, out);
    }
}